// Round 1
// baseline (505.706 us; speedup 1.0000x reference)
//
#include <hip/hip_runtime.h>
#include <hip/hip_bf16.h>

#define S_ 4096
#define D_ 1024
#define H_ 16
#define DK_ 64
#define DV_ 64

typedef short bf16x8 __attribute__((ext_vector_type(8)));
typedef float floatx4 __attribute__((ext_vector_type(4)));
using bf16 = __hip_bfloat16;

// ---------------------------------------------------------------------------
// Kernel 1: per-head QKV projection.  C[s,n] = sum_d x[s,d] * W[d,n]
// Tile: 64 (s) x 64 (n=DK), BK=32.  Q,K stored [H][S][DK]; V stored
// transposed [H][DV][S] so attention's PV B-fragments are contiguous.
// ---------------------------------------------------------------------------
__global__ __launch_bounds__(256)
void qkv_proj(const float* __restrict__ x,
              const float* __restrict__ Wq,
              const float* __restrict__ Wk,
              const float* __restrict__ Wv,
              bf16* __restrict__ Qb, bf16* __restrict__ Kb, bf16* __restrict__ Vtb)
{
    const int m0    = blockIdx.x * 64;   // s tile
    const int h     = blockIdx.y;
    const int which = blockIdx.z;        // 0=Q, 1=K, 2=V
    const float* W = (which == 0 ? Wq : which == 1 ? Wk : Wv) + (size_t)h * D_ * DK_;

    __shared__ __align__(16) bf16 xa[64][40];  // [m][k], stride 40 (80B, 16B-aligned, 2-way banks)
    __shared__ __align__(16) bf16 wt[64][40];  // [n][k]  (W transposed)

    const int t    = threadIdx.x;
    const int lane = t & 63;
    const int w    = t >> 6;
    const int l15  = lane & 15;
    const int quad = lane >> 4;

    const floatx4 fzero = {0.f, 0.f, 0.f, 0.f};
    floatx4 acc[4];
    #pragma unroll
    for (int nt = 0; nt < 4; nt++) acc[nt] = fzero;

    for (int kk = 0; kk < D_; kk += 32) {
        // stage x tile [64][32] -> bf16
        {
            int r = t >> 2, c0 = (t & 3) * 8;
            const float* src = x + (size_t)(m0 + r) * D_ + kk + c0;
            #pragma unroll
            for (int i = 0; i < 8; i++) xa[r][c0 + i] = __float2bfloat16(src[i]);
        }
        // stage W tile [32][64] transposed -> wt[n][k]
        {
            int c = t >> 3, n0 = (t & 7) * 8;
            const float* src = W + (size_t)(kk + c) * DK_ + n0;
            #pragma unroll
            for (int i = 0; i < 8; i++) wt[n0 + i][c] = __float2bfloat16(src[i]);
        }
        __syncthreads();
        bf16x8 a = *(const bf16x8*)&xa[w * 16 + l15][quad * 8];
        #pragma unroll
        for (int nt = 0; nt < 4; nt++) {
            bf16x8 b = *(const bf16x8*)&wt[nt * 16 + l15][quad * 8];
            acc[nt] = __builtin_amdgcn_mfma_f32_16x16x32_bf16(a, b, acc[nt], 0, 0, 0);
        }
        __syncthreads();
    }

    // epilogue: C/D layout col=lane&15, row=quad*4+reg
    #pragma unroll
    for (int nt = 0; nt < 4; nt++) {
        #pragma unroll
        for (int r = 0; r < 4; r++) {
            int row = m0 + w * 16 + quad * 4 + r;  // s index
            int col = nt * 16 + l15;               // dk/dv index
            bf16 val = __float2bfloat16(acc[nt][r]);
            if (which == 0)      Qb[((size_t)h * S_ + row) * DK_ + col] = val;
            else if (which == 1) Kb[((size_t)h * S_ + row) * DK_ + col] = val;
            else                 Vtb[((size_t)h * DV_ + col) * S_ + row] = val;
        }
    }
}

// ---------------------------------------------------------------------------
// Kernel 2: flash attention.  Block = 64 q-rows of one head; loop over 64-key
// tiles; online softmax in C-layout registers; P->LDS->A-layout for PV.
// Writes concat layout Cat[s][h*64+dv] in bf16.
// ---------------------------------------------------------------------------
__global__ __launch_bounds__(256)
void attn(const bf16* __restrict__ Qb, const bf16* __restrict__ Kb,
          const bf16* __restrict__ Vtb, bf16* __restrict__ Cat)
{
    const int m0 = blockIdx.x * 64;
    const int h  = blockIdx.y;

    __shared__ __align__(16) bf16 qa[64][72];  // [q_row][dk]
    __shared__ __align__(16) bf16 ka[64][72];  // [key][dk]   (= B^T for QK^T)
    __shared__ __align__(16) bf16 vt[64][72];  // [dv][key]   (= B^T for PV)
    __shared__ __align__(16) bf16 pl[64][72];  // [q_row][key] (P in A-layout)

    const int t    = threadIdx.x;
    const int lane = t & 63;
    const int w    = t >> 6;
    const int l15  = lane & 15;
    const int quad = lane >> 4;

    // stage Q once
    {
        int r = t >> 2, c0 = (t & 3) * 16;
        const bf16* src = Qb + ((size_t)h * S_ + m0 + r) * DK_ + c0;
        #pragma unroll
        for (int i = 0; i < 16; i++) qa[r][c0 + i] = src[i];
    }

    const floatx4 fzero = {0.f, 0.f, 0.f, 0.f};
    float m_run[4], l_run[4];
    floatx4 acc_o[4];
    #pragma unroll
    for (int r = 0; r < 4; r++) { m_run[r] = -1e30f; l_run[r] = 0.f; }
    #pragma unroll
    for (int nt = 0; nt < 4; nt++) acc_o[nt] = fzero;

    __syncthreads();

    for (int kt = 0; kt < S_ / 64; kt++) {
        const int key0 = kt * 64;
        // stage K tile and V^T tile
        {
            int r = t >> 2, c0 = (t & 3) * 16;
            const bf16* srck = Kb + ((size_t)h * S_ + key0 + r) * DK_ + c0;
            #pragma unroll
            for (int i = 0; i < 16; i++) ka[r][c0 + i] = srck[i];
            const bf16* srcv = Vtb + ((size_t)h * DV_ + r) * S_ + key0 + c0;
            #pragma unroll
            for (int i = 0; i < 16; i++) vt[r][c0 + i] = srcv[i];
        }
        __syncthreads();

        // S = Q K^T : wave w owns q-rows w*16 .. w*16+15, all 64 key-cols
        floatx4 sc[4];
        #pragma unroll
        for (int nt = 0; nt < 4; nt++) sc[nt] = fzero;
        #pragma unroll
        for (int ks = 0; ks < 64; ks += 32) {
            bf16x8 a = *(const bf16x8*)&qa[w * 16 + l15][ks + quad * 8];
            #pragma unroll
            for (int nt = 0; nt < 4; nt++) {
                bf16x8 b = *(const bf16x8*)&ka[nt * 16 + l15][ks + quad * 8];
                sc[nt] = __builtin_amdgcn_mfma_f32_16x16x32_bf16(a, b, sc[nt], 0, 0, 0);
            }
        }

        // online softmax: row (quad*4+r) lives in this quad's 16 lanes
        #pragma unroll
        for (int r = 0; r < 4; r++) {
            float mx = -1e30f;
            #pragma unroll
            for (int nt = 0; nt < 4; nt++) {
                float v = sc[nt][r] * 0.125f;   // 1/sqrt(DK)
                sc[nt][r] = v;
                mx = fmaxf(mx, v);
            }
            #pragma unroll
            for (int d = 1; d < 16; d <<= 1) mx = fmaxf(mx, __shfl_xor(mx, d, 16));
            float m_new = fmaxf(m_run[r], mx);
            float alpha = __expf(m_run[r] - m_new);
            float rs = 0.f;
            #pragma unroll
            for (int nt = 0; nt < 4; nt++) {
                float p = __expf(sc[nt][r] - m_new);
                sc[nt][r] = p;
                rs += p;
            }
            #pragma unroll
            for (int d = 1; d < 16; d <<= 1) rs += __shfl_xor(rs, d, 16);
            l_run[r] = l_run[r] * alpha + rs;
            m_run[r] = m_new;
            #pragma unroll
            for (int nt = 0; nt < 4; nt++) acc_o[nt][r] *= alpha;
        }

        // P (C-layout regs) -> LDS A-layout
        #pragma unroll
        for (int nt = 0; nt < 4; nt++)
            #pragma unroll
            for (int r = 0; r < 4; r++)
                pl[w * 16 + quad * 4 + r][nt * 16 + l15] = __float2bfloat16(sc[nt][r]);
        __syncthreads();

        // O += P V  (A = P [q_row][key], B^T = vt [dv][key])
        #pragma unroll
        for (int ks = 0; ks < 64; ks += 32) {
            bf16x8 a = *(const bf16x8*)&pl[w * 16 + l15][ks + quad * 8];
            #pragma unroll
            for (int nt = 0; nt < 4; nt++) {
                bf16x8 b = *(const bf16x8*)&vt[nt * 16 + l15][ks + quad * 8];
                acc_o[nt] = __builtin_amdgcn_mfma_f32_16x16x32_bf16(a, b, acc_o[nt], 0, 0, 0);
            }
        }
        __syncthreads();
    }

    // epilogue: normalize, write concat layout bf16
    #pragma unroll
    for (int nt = 0; nt < 4; nt++) {
        #pragma unroll
        for (int r = 0; r < 4; r++) {
            float o = acc_o[nt][r] / l_run[r];
            int s = m0 + w * 16 + quad * 4 + r;
            int c = h * 64 + nt * 16 + l15;
            Cat[(size_t)s * (H_ * DV_) + c] = __float2bfloat16(o);
        }
    }
}

// ---------------------------------------------------------------------------
// Kernel 3: output projection.  out[s,d] = sum_k cat[s,k] * Wc[k,d] + bc[d]
// ---------------------------------------------------------------------------
__global__ __launch_bounds__(256)
void out_proj(const bf16* __restrict__ Cat, const float* __restrict__ Wc,
              const float* __restrict__ bc, float* __restrict__ out)
{
    const int m0 = blockIdx.x * 64;   // s
    const int n0 = blockIdx.y * 64;   // d
    __shared__ __align__(16) bf16 ca[64][40];
    __shared__ __align__(16) bf16 wt[64][40];

    const int t    = threadIdx.x;
    const int lane = t & 63;
    const int w    = t >> 6;
    const int l15  = lane & 15;
    const int quad = lane >> 4;

    const floatx4 fzero = {0.f, 0.f, 0.f, 0.f};
    floatx4 acc[4];
    #pragma unroll
    for (int nt = 0; nt < 4; nt++) acc[nt] = fzero;

    for (int kk = 0; kk < H_ * DV_; kk += 32) {
        {
            int r = t >> 2, c0 = (t & 3) * 8;
            const bf16* src = Cat + (size_t)(m0 + r) * (H_ * DV_) + kk + c0;
            #pragma unroll
            for (int i = 0; i < 8; i++) ca[r][c0 + i] = src[i];
        }
        {
            int c = t >> 3, nn0 = (t & 7) * 8;
            const float* src = Wc + (size_t)(kk + c) * D_ + n0 + nn0;
            #pragma unroll
            for (int i = 0; i < 8; i++) wt[nn0 + i][c] = __float2bfloat16(src[i]);
        }
        __syncthreads();
        bf16x8 a = *(const bf16x8*)&ca[w * 16 + l15][quad * 8];
        #pragma unroll
        for (int nt = 0; nt < 4; nt++) {
            bf16x8 b = *(const bf16x8*)&wt[nt * 16 + l15][quad * 8];
            acc[nt] = __builtin_amdgcn_mfma_f32_16x16x32_bf16(a, b, acc[nt], 0, 0, 0);
        }
        __syncthreads();
    }

    #pragma unroll
    for (int nt = 0; nt < 4; nt++) {
        #pragma unroll
        for (int r = 0; r < 4; r++) {
            int row = m0 + w * 16 + quad * 4 + r;
            int col = n0 + nt * 16 + l15;
            out[(size_t)row * D_ + col] = acc[nt][r] + bc[col];
        }
    }
}

extern "C" void kernel_launch(void* const* d_in, const int* in_sizes, int n_in,
                              void* d_out, int out_size, void* d_ws, size_t ws_size,
                              hipStream_t stream)
{
    const float* x  = (const float*)d_in[0];
    const float* Wq = (const float*)d_in[1];
    const float* Wk = (const float*)d_in[2];
    const float* Wv = (const float*)d_in[3];
    const float* Wc = (const float*)d_in[4];
    const float* bc = (const float*)d_in[5];
    float* out = (float*)d_out;

    bf16* Qb  = (bf16*)d_ws;                    // [H][S][DK]
    bf16* Kb  = Qb  + (size_t)H_ * S_ * DK_;    // [H][S][DK]
    bf16* Vtb = Kb  + (size_t)H_ * S_ * DK_;    // [H][DV][S]
    bf16* Cat = Vtb + (size_t)H_ * DV_ * S_;    // [S][H*DV]

    qkv_proj<<<dim3(S_ / 64, H_, 3), 256, 0, stream>>>(x, Wq, Wk, Wv, Qb, Kb, Vtb);
    attn<<<dim3(S_ / 64, H_), 256, 0, stream>>>(Qb, Kb, Vtb, Cat);
    out_proj<<<dim3(S_ / 64, D_ / 64), 256, 0, stream>>>(Cat, Wc, bc, out);
}

// Round 2
// 271.799 us; speedup vs baseline: 1.8606x; 1.8606x over previous
//
#include <hip/hip_runtime.h>
#include <hip/hip_bf16.h>

#define S_ 4096
#define D_ 1024
#define H_ 16
#define DK_ 64
#define DV_ 64

typedef short bf16x8 __attribute__((ext_vector_type(8)));
typedef float floatx4 __attribute__((ext_vector_type(4)));
using bf16 = __hip_bfloat16;

#define MFMA16(a, b, c) __builtin_amdgcn_mfma_f32_16x16x32_bf16(a, b, c, 0, 0, 0)

// async global->LDS, 16B per lane. lds ptr must be wave-uniform; HW adds lane*16.
__device__ __forceinline__ void stage16(const void* g, void* l) {
    __builtin_amdgcn_global_load_lds(
        (const __attribute__((address_space(1))) void*)g,
        (__attribute__((address_space(3))) void*)l, 16, 0, 0);
}

// read a bf16x8 fragment from a swizzled [rows][64] LDS tile.
// swizzle: 16B-chunk index ^= (row & 7)  (matches staging layout below)
__device__ __forceinline__ bf16x8 ldsfrag(const bf16* base, int row, int chunk) {
    return *(const bf16x8*)(base + row * 64 + ((chunk ^ (row & 7)) << 3));
}

// ---------------------------------------------------------------------------
// prep: x fp32 -> bf16 (same layout)
// ---------------------------------------------------------------------------
__global__ __launch_bounds__(256)
void cvt_x(const float* __restrict__ x, bf16* __restrict__ xb)
{
    int i = (blockIdx.x * 256 + threadIdx.x) * 8;
    float4 a = *(const float4*)(x + i);
    float4 b = *(const float4*)(x + i + 4);
    union { bf16x8 v; bf16 e[8]; } u;
    u.e[0] = __float2bfloat16(a.x); u.e[1] = __float2bfloat16(a.y);
    u.e[2] = __float2bfloat16(a.z); u.e[3] = __float2bfloat16(a.w);
    u.e[4] = __float2bfloat16(b.x); u.e[5] = __float2bfloat16(b.y);
    u.e[6] = __float2bfloat16(b.z); u.e[7] = __float2bfloat16(b.w);
    *(bf16x8*)(xb + i) = u.v;
}

// ---------------------------------------------------------------------------
// prep: transpose + convert (+scale). src fp32 [R][C] -> dst bf16 [C][R].
// blockIdx.z indexes matrices (stride in elements).
// ---------------------------------------------------------------------------
__global__ __launch_bounds__(256)
void transpose_cvt(const float* __restrict__ src, bf16* __restrict__ dst,
                   int R, int C, long srcMatStride, long dstMatStride, float scale)
{
    const float* s = src + (size_t)blockIdx.z * srcMatStride;
    bf16* d = dst + (size_t)blockIdx.z * dstMatStride;
    int r0 = blockIdx.x * 64, c0 = blockIdx.y * 64;
    __shared__ float ls[64][65];
    int t = threadIdx.x;
    {
        int r = t >> 2, cseg = (t & 3) * 16;
        const float* sp = s + (size_t)(r0 + r) * C + c0 + cseg;
        #pragma unroll
        for (int i = 0; i < 16; i += 4) {
            float4 v = *(const float4*)(sp + i);
            ls[r][cseg + i + 0] = v.x; ls[r][cseg + i + 1] = v.y;
            ls[r][cseg + i + 2] = v.z; ls[r][cseg + i + 3] = v.w;
        }
    }
    __syncthreads();
    {
        int c = t >> 2, rseg = (t & 3) * 16;
        bf16* dp = d + (size_t)(c0 + c) * R + r0 + rseg;
        #pragma unroll
        for (int i = 0; i < 16; i++) dp[i] = __float2bfloat16(ls[rseg + i][c] * scale);
    }
}

// ---------------------------------------------------------------------------
// Kernel 1: fused QKV projection. One block = 128 s-rows x (Q|K|V 192 cols)
// for one head. A = x_bf [s][d], B^T = Wt [which][h][n][d] (pre-transposed,
// Wq pre-scaled by 1/8). Double-buffered global_load_lds staging, BK=64.
// ---------------------------------------------------------------------------
__global__ __launch_bounds__(256)
void qkv_gemm(const bf16* __restrict__ xb, const bf16* __restrict__ Wt,
              bf16* __restrict__ Qb, bf16* __restrict__ Kb, bf16* __restrict__ Vtb)
{
    const int m0 = blockIdx.x * 128;
    const int h  = blockIdx.y;
    __shared__ __align__(16) bf16 xa[2][128 * 64];   // 32 KB
    __shared__ __align__(16) bf16 wb[2][192 * 64];   // 48 KB

    const int t = threadIdx.x, lane = t & 63, w = t >> 6;
    const int l15 = lane & 15, quad = lane >> 4;

    auto stage_x = [&](int buf, int kk) {
        #pragma unroll
        for (int j = 0; j < 4; j++) {
            int c = (j * 4 + w) * 64 + lane;
            int row = c >> 3, ch = (c & 7) ^ (row & 7);
            stage16((const char*)(xb + (size_t)(m0 + row) * D_ + kk) + ch * 16,
                    (char*)&xa[buf][0] + (j * 4 + w) * 1024);
        }
    };
    auto stage_w = [&](int buf, int kk) {
        #pragma unroll
        for (int j = 0; j < 6; j++) {
            int c = (j * 4 + w) * 64 + lane;
            int row = c >> 3, ch = (c & 7) ^ (row & 7);   // row = n' in 0..191
            const bf16* g = Wt + (size_t)(row >> 6) * (H_ * 64 * 1024)
                               + (size_t)h * (64 * 1024)
                               + (size_t)(row & 63) * 1024 + kk;
            stage16((const char*)g + ch * 16, (char*)&wb[buf][0] + (j * 4 + w) * 1024);
        }
    };

    const floatx4 fz = {0.f, 0.f, 0.f, 0.f};
    floatx4 acc[2][12];
    #pragma unroll
    for (int mt = 0; mt < 2; mt++)
        #pragma unroll
        for (int nt = 0; nt < 12; nt++) acc[mt][nt] = fz;

    stage_x(0, 0); stage_w(0, 0);
    for (int kt = 0; kt < 16; kt++) {
        int cur = kt & 1;
        __syncthreads();                       // staging(cur) landed; prev buf free
        if (kt < 15) { stage_x(cur ^ 1, (kt + 1) * 64); stage_w(cur ^ 1, (kt + 1) * 64); }
        #pragma unroll
        for (int ks = 0; ks < 2; ks++) {
            bf16x8 a0 = ldsfrag(&xa[cur][0], w * 32 + l15,      ks * 4 + quad);
            bf16x8 a1 = ldsfrag(&xa[cur][0], w * 32 + 16 + l15, ks * 4 + quad);
            #pragma unroll
            for (int nt = 0; nt < 12; nt++) {
                bf16x8 b = ldsfrag(&wb[cur][0], nt * 16 + l15, ks * 4 + quad);
                acc[0][nt] = MFMA16(a0, b, acc[0][nt]);
                acc[1][nt] = MFMA16(a1, b, acc[1][nt]);
            }
        }
    }

    #pragma unroll
    for (int nt = 0; nt < 12; nt++) {
        int which = nt >> 2;
        int col = (nt & 3) * 16 + l15;
        #pragma unroll
        for (int mt = 0; mt < 2; mt++)
            #pragma unroll
            for (int r = 0; r < 4; r++) {
                int s = m0 + w * 32 + mt * 16 + quad * 4 + r;
                bf16 val = __float2bfloat16(acc[mt][nt][r]);
                if (which == 0)      Qb[((size_t)h * S_ + s) * 64 + col] = val;
                else if (which == 1) Kb[((size_t)h * S_ + s) * 64 + col] = val;
                else                 Vtb[((size_t)h * 64 + col) * S_ + s] = val;
            }
    }
}

// ---------------------------------------------------------------------------
// Kernel 2: attention, no-max softmax (scale folded into Wq), 128 q-rows per
// block (4 waves x 32 rows), 64-key tiles, Q frags in registers, K/V double-
// buffered via global_load_lds, ONE barrier per iteration. P is per-wave
// private (rows w*32..w*32+31) -> no barrier around the P LDS round-trip.
// ---------------------------------------------------------------------------
__global__ __launch_bounds__(256)
void attn(const bf16* __restrict__ Qb, const bf16* __restrict__ Kb,
          const bf16* __restrict__ Vtb, bf16* __restrict__ Cat)
{
    const int m0 = blockIdx.x * 128;
    const int h  = blockIdx.y;
    __shared__ __align__(16) bf16 ka[2][64 * 64];   // 16 KB, swizzled [key][dk]
    __shared__ __align__(16) bf16 vt[2][64 * 64];   // 16 KB, swizzled [dv][key]
    __shared__ __align__(16) bf16 pl[128 * 72];     // 18 KB: Q staging, then P (stride 72)

    const int t = threadIdx.x, lane = t & 63, w = t >> 6;
    const int l15 = lane & 15, quad = lane >> 4;

    auto stage_kv = [&](int buf, int key0) {
        const char* kg = (const char*)(Kb + ((size_t)h * S_ + key0) * 64);
        #pragma unroll
        for (int j = 0; j < 2; j++) {
            int c = (j * 4 + w) * 64 + lane;
            int row = c >> 3, ch = (c & 7) ^ (row & 7);
            stage16(kg + row * 128 + ch * 16, (char*)&ka[buf][0] + (j * 4 + w) * 1024);
        }
        const char* vg = (const char*)(Vtb + (size_t)h * 64 * S_ + key0);
        #pragma unroll
        for (int j = 0; j < 2; j++) {
            int c = (j * 4 + w) * 64 + lane;
            int row = c >> 3, ch = (c & 7) ^ (row & 7);   // row = dv
            stage16(vg + (size_t)row * (S_ * 2) + ch * 16, (char*)&vt[buf][0] + (j * 4 + w) * 1024);
        }
    };

    // stage Q (16 KB) into pl region as flat swizzled [128][64]
    {
        const char* qg = (const char*)(Qb + ((size_t)h * S_ + m0) * 64);
        #pragma unroll
        for (int j = 0; j < 4; j++) {
            int c = (j * 4 + w) * 64 + lane;
            int row = c >> 3, ch = (c & 7) ^ (row & 7);
            stage16(qg + row * 128 + ch * 16, (char*)pl + (j * 4 + w) * 1024);
        }
    }
    stage_kv(0, 0);
    __syncthreads();

    bf16x8 qf[2][2];
    #pragma unroll
    for (int mt = 0; mt < 2; mt++)
        #pragma unroll
        for (int ks = 0; ks < 2; ks++)
            qf[mt][ks] = ldsfrag((const bf16*)pl, w * 32 + mt * 16 + l15, ks * 4 + quad);
    __syncthreads();   // all waves done reading Q before anyone writes P into pl

    const floatx4 fz = {0.f, 0.f, 0.f, 0.f};
    floatx4 acc[2][4];
    float rs[2][4];
    #pragma unroll
    for (int mt = 0; mt < 2; mt++) {
        #pragma unroll
        for (int nt = 0; nt < 4; nt++) acc[mt][nt] = fz;
        #pragma unroll
        for (int r = 0; r < 4; r++) rs[mt][r] = 0.f;
    }

    for (int kt = 0; kt < S_ / 64; kt++) {
        const int cur = kt & 1;
        if (kt + 1 < S_ / 64) stage_kv(cur ^ 1, (kt + 1) * 64);   // prefetch, lands by barrier

        // S = Q K^T
        floatx4 sc[2][4];
        #pragma unroll
        for (int mt = 0; mt < 2; mt++)
            #pragma unroll
            for (int nt = 0; nt < 4; nt++) sc[mt][nt] = fz;
        #pragma unroll
        for (int ks = 0; ks < 2; ks++) {
            #pragma unroll
            for (int nt = 0; nt < 4; nt++) {
                bf16x8 b = ldsfrag(&ka[cur][0], nt * 16 + l15, ks * 4 + quad);
                sc[0][nt] = MFMA16(qf[0][ks], b, sc[0][nt]);
                sc[1][nt] = MFMA16(qf[1][ks], b, sc[1][nt]);
            }
        }

        // p = exp(s); per-lane partial row sums; P -> LDS (A-layout, own rows)
        #pragma unroll
        for (int mt = 0; mt < 2; mt++)
            #pragma unroll
            for (int nt = 0; nt < 4; nt++)
                #pragma unroll
                for (int r = 0; r < 4; r++) {
                    float p = __expf(sc[mt][nt][r]);
                    rs[mt][r] += p;
                    pl[(w * 32 + mt * 16 + quad * 4 + r) * 72 + nt * 16 + l15] =
                        __float2bfloat16(p);
                }
        asm volatile("s_waitcnt lgkmcnt(0)" ::: "memory");  // P visible to own wave's reads

        // O += P V
        #pragma unroll
        for (int ks = 0; ks < 2; ks++) {
            bf16x8 a0 = *(const bf16x8*)(pl + (w * 32 + l15) * 72 + ks * 32 + quad * 8);
            bf16x8 a1 = *(const bf16x8*)(pl + (w * 32 + 16 + l15) * 72 + ks * 32 + quad * 8);
            #pragma unroll
            for (int nt = 0; nt < 4; nt++) {
                bf16x8 b = ldsfrag(&vt[cur][0], nt * 16 + l15, ks * 4 + quad);
                acc[0][nt] = MFMA16(a0, b, acc[0][nt]);
                acc[1][nt] = MFMA16(a1, b, acc[1][nt]);
            }
        }
        __syncthreads();   // staging(next) landed; all waves done with cur
    }

    // epilogue: reduce row sums across the 16 lanes of each quad-group, write Cat
    #pragma unroll
    for (int mt = 0; mt < 2; mt++)
        #pragma unroll
        for (int r = 0; r < 4; r++) {
            float s_ = rs[mt][r];
            s_ += __shfl_xor(s_, 1, 16);
            s_ += __shfl_xor(s_, 2, 16);
            s_ += __shfl_xor(s_, 4, 16);
            s_ += __shfl_xor(s_, 8, 16);
            float inv = 1.0f / s_;
            int srow = m0 + w * 32 + mt * 16 + quad * 4 + r;
            #pragma unroll
            for (int nt = 0; nt < 4; nt++)
                Cat[(size_t)srow * (H_ * DV_) + h * 64 + nt * 16 + l15] =
                    __float2bfloat16(acc[mt][nt][r] * inv);
        }
}

// ---------------------------------------------------------------------------
// Kernel 3: output projection. 128x128 tile, BK=64, A = Cat bf16 [s][1024],
// B^T = Wct bf16 [d][k] (pre-transposed). Double-buffered staging. +bias.
// ---------------------------------------------------------------------------
__global__ __launch_bounds__(256)
void out_proj(const bf16* __restrict__ Cat, const bf16* __restrict__ Wct,
              const float* __restrict__ bc, float* __restrict__ out)
{
    const int m0 = blockIdx.x * 128;
    const int n0 = blockIdx.y * 128;
    __shared__ __align__(16) bf16 ca[2][128 * 64];   // 32 KB
    __shared__ __align__(16) bf16 wb[2][128 * 64];   // 32 KB

    const int t = threadIdx.x, lane = t & 63, w = t >> 6;
    const int l15 = lane & 15, quad = lane >> 4;

    auto stage_a = [&](int buf, int kk) {
        #pragma unroll
        for (int j = 0; j < 4; j++) {
            int c = (j * 4 + w) * 64 + lane;
            int row = c >> 3, ch = (c & 7) ^ (row & 7);
            stage16((const char*)(Cat + (size_t)(m0 + row) * D_ + kk) + ch * 16,
                    (char*)&ca[buf][0] + (j * 4 + w) * 1024);
        }
    };
    auto stage_b = [&](int buf, int kk) {
        #pragma unroll
        for (int j = 0; j < 4; j++) {
            int c = (j * 4 + w) * 64 + lane;
            int row = c >> 3, ch = (c & 7) ^ (row & 7);
            stage16((const char*)(Wct + (size_t)(n0 + row) * D_ + kk) + ch * 16,
                    (char*)&wb[buf][0] + (j * 4 + w) * 1024);
        }
    };

    const floatx4 fz = {0.f, 0.f, 0.f, 0.f};
    floatx4 acc[2][8];
    #pragma unroll
    for (int mt = 0; mt < 2; mt++)
        #pragma unroll
        for (int nt = 0; nt < 8; nt++) acc[mt][nt] = fz;

    stage_a(0, 0); stage_b(0, 0);
    for (int kt = 0; kt < 16; kt++) {
        int cur = kt & 1;
        __syncthreads();
        if (kt < 15) { stage_a(cur ^ 1, (kt + 1) * 64); stage_b(cur ^ 1, (kt + 1) * 64); }
        #pragma unroll
        for (int ks = 0; ks < 2; ks++) {
            bf16x8 a0 = ldsfrag(&ca[cur][0], w * 32 + l15,      ks * 4 + quad);
            bf16x8 a1 = ldsfrag(&ca[cur][0], w * 32 + 16 + l15, ks * 4 + quad);
            #pragma unroll
            for (int nt = 0; nt < 8; nt++) {
                bf16x8 b = ldsfrag(&wb[cur][0], nt * 16 + l15, ks * 4 + quad);
                acc[0][nt] = MFMA16(a0, b, acc[0][nt]);
                acc[1][nt] = MFMA16(a1, b, acc[1][nt]);
            }
        }
    }

    #pragma unroll
    for (int nt = 0; nt < 8; nt++) {
        int col = n0 + nt * 16 + l15;
        float bias = bc[col];
        #pragma unroll
        for (int mt = 0; mt < 2; mt++)
            #pragma unroll
            for (int r = 0; r < 4; r++) {
                int row = m0 + w * 32 + mt * 16 + quad * 4 + r;
                out[(size_t)row * D_ + col] = acc[mt][nt][r] + bias;
            }
    }
}

extern "C" void kernel_launch(void* const* d_in, const int* in_sizes, int n_in,
                              void* d_out, int out_size, void* d_ws, size_t ws_size,
                              hipStream_t stream)
{
    const float* x  = (const float*)d_in[0];
    const float* Wq = (const float*)d_in[1];
    const float* Wk = (const float*)d_in[2];
    const float* Wv = (const float*)d_in[3];
    const float* Wc = (const float*)d_in[4];
    const float* bc = (const float*)d_in[5];
    float* out = (float*)d_out;

    // workspace layout (bf16 elements); Cat aliases x_bf (x_bf dead after qkv_gemm)
    bf16* xb  = (bf16*)d_ws;                            // [S][D]        8 MB
    bf16* Cat = xb;                                     // [S][H*DV]     (alias)
    bf16* Wt  = xb  + (size_t)S_ * D_;                  // [3][H][64][D] 6 MB
    bf16* Wct = Wt  + (size_t)3 * H_ * 64 * D_;         // [D][H*DV]     2 MB
    bf16* Qb  = Wct + (size_t)D_ * H_ * DV_;            // [H][S][64]    8 MB
    bf16* Kb  = Qb  + (size_t)H_ * S_ * 64;             // [H][S][64]    8 MB
    bf16* Vtb = Kb  + (size_t)H_ * S_ * 64;             // [H][64][S]    8 MB

    const long wMat = (long)D_ * 64;                    // 65536
    const long wHead = (long)H_ * 64 * D_;              // per-which stride in Wt

    cvt_x<<<dim3(S_ * D_ / (256 * 8)), 256, 0, stream>>>(x, xb);
    // Wq pre-scaled by 1/sqrt(DK) = 0.125 so attention needs no score scaling
    transpose_cvt<<<dim3(16, 1, 16), 256, 0, stream>>>(Wq, Wt,             1024, 64, wMat, wMat, 0.125f);
    transpose_cvt<<<dim3(16, 1, 16), 256, 0, stream>>>(Wk, Wt + wHead,     1024, 64, wMat, wMat, 1.0f);
    transpose_cvt<<<dim3(16, 1, 16), 256, 0, stream>>>(Wv, Wt + 2 * wHead, 1024, 64, wMat, wMat, 1.0f);
    transpose_cvt<<<dim3(16, 16, 1), 256, 0, stream>>>(Wc, Wct,            1024, 1024, 0, 0, 1.0f);

    qkv_gemm<<<dim3(S_ / 128, H_), 256, 0, stream>>>(xb, Wt, Qb, Kb, Vtb);
    attn<<<dim3(S_ / 128, H_), 256, 0, stream>>>(Qb, Kb, Vtb, Cat);
    out_proj<<<dim3(S_ / 128, D_ / 128), 256, 0, stream>>>(Cat, Wct, bc, out);
}

// Round 3
// 269.746 us; speedup vs baseline: 1.8747x; 1.0076x over previous
//
#include <hip/hip_runtime.h>
#include <hip/hip_bf16.h>

#define S_ 4096
#define D_ 1024
#define H_ 16
#define DK_ 64
#define DV_ 64

typedef short bf16x8 __attribute__((ext_vector_type(8)));
typedef float floatx4 __attribute__((ext_vector_type(4)));
using bf16 = __hip_bfloat16;

#define MFMA16(a, b, c) __builtin_amdgcn_mfma_f32_16x16x32_bf16(a, b, c, 0, 0, 0)

#if __has_builtin(__builtin_amdgcn_exp2f)
#define EXP2(x) __builtin_amdgcn_exp2f(x)
#else
#define EXP2(x) exp2f(x)
#endif

// async global->LDS, 16B per lane. lds ptr wave-uniform; HW adds lane*16.
__device__ __forceinline__ void stage16(const void* g, void* l) {
    __builtin_amdgcn_global_load_lds(
        (const __attribute__((address_space(1))) void*)g,
        (__attribute__((address_space(3))) void*)l, 16, 0, 0);
}

// read a bf16x8 fragment from a swizzled [rows][64] LDS tile.
// swizzle: 16B-chunk index ^= (row & 7)
__device__ __forceinline__ bf16x8 ldsfrag(const bf16* base, int row, int chunk) {
    return *(const bf16x8*)(base + row * 64 + (((chunk ^ (row & 7))) << 3));
}

__device__ __forceinline__ unsigned short bfbits(float f) {
    union { bf16 h; unsigned short u; } c; c.h = __float2bfloat16(f); return c.u;
}

// ---------------------------------------------------------------------------
// prep: x fp32 -> bf16
// ---------------------------------------------------------------------------
__global__ __launch_bounds__(256)
void cvt_x(const float* __restrict__ x, bf16* __restrict__ xb)
{
    int i = (blockIdx.x * 256 + threadIdx.x) * 8;
    float4 a = *(const float4*)(x + i);
    float4 b = *(const float4*)(x + i + 4);
    ushort4 lo, hi;
    lo.x = bfbits(a.x); lo.y = bfbits(a.y); lo.z = bfbits(a.z); lo.w = bfbits(a.w);
    hi.x = bfbits(b.x); hi.y = bfbits(b.y); hi.z = bfbits(b.z); hi.w = bfbits(b.w);
    *(ushort4*)(xb + i) = lo;
    *(ushort4*)(xb + i + 4) = hi;
}

// ---------------------------------------------------------------------------
// prep: merged Wq/Wk/Wv transpose+cvt. z = which*16 + h.
// src W[h] is [1024][64]; dst rows n = which*1024 + h*64 + (0..63), [n][1024].
// Wq pre-scaled by (1/sqrt(DK)) * log2(e) so attention uses exp2 directly.
// ---------------------------------------------------------------------------
__global__ __launch_bounds__(256)
void tr_qkv(const float* __restrict__ Wq, const float* __restrict__ Wk,
            const float* __restrict__ Wv, bf16* __restrict__ Wt)
{
    const int z = blockIdx.z, which = z >> 4, h = z & 15;
    const float* s = (which == 0 ? Wq : which == 1 ? Wk : Wv) + (size_t)h * D_ * 64;
    bf16* d = Wt + ((size_t)which * 1024 + h * 64) * D_;
    const float scale = (which == 0) ? 0.125f * 1.44269504088896340736f : 1.0f;
    const int r0 = blockIdx.x * 64;
    __shared__ float ls[64][65];
    int t = threadIdx.x;
    {
        int r = t >> 2, cseg = (t & 3) * 16;
        const float* sp = s + (size_t)(r0 + r) * 64 + cseg;
        #pragma unroll
        for (int i = 0; i < 16; i += 4) {
            float4 v = *(const float4*)(sp + i);
            ls[r][cseg + i + 0] = v.x; ls[r][cseg + i + 1] = v.y;
            ls[r][cseg + i + 2] = v.z; ls[r][cseg + i + 3] = v.w;
        }
    }
    __syncthreads();
    {
        int c = t >> 2, rseg = (t & 3) * 16;
        bf16* dp = d + (size_t)c * D_ + r0 + rseg;
        #pragma unroll
        for (int i = 0; i < 16; i++) dp[i] = __float2bfloat16(ls[rseg + i][c] * scale);
    }
}

// ---------------------------------------------------------------------------
// prep: generic transpose+cvt for Wc: [1024][1024] -> [1024][1024]^T
// ---------------------------------------------------------------------------
__global__ __launch_bounds__(256)
void tr_wc(const float* __restrict__ src, bf16* __restrict__ dst)
{
    int r0 = blockIdx.x * 64, c0 = blockIdx.y * 64;
    __shared__ float ls[64][65];
    int t = threadIdx.x;
    {
        int r = t >> 2, cseg = (t & 3) * 16;
        const float* sp = src + (size_t)(r0 + r) * D_ + c0 + cseg;
        #pragma unroll
        for (int i = 0; i < 16; i += 4) {
            float4 v = *(const float4*)(sp + i);
            ls[r][cseg + i + 0] = v.x; ls[r][cseg + i + 1] = v.y;
            ls[r][cseg + i + 2] = v.z; ls[r][cseg + i + 3] = v.w;
        }
    }
    __syncthreads();
    {
        int c = t >> 2, rseg = (t & 3) * 16;
        bf16* dp = dst + (size_t)(c0 + c) * D_ + r0 + rseg;
        #pragma unroll
        for (int i = 0; i < 16; i++) dp[i] = __float2bfloat16(ls[rseg + i][c]);
    }
}

// ---------------------------------------------------------------------------
// Kernel 1: fused QKV GEMM. C[4096][3072] = xb[4096][1024] . Wt^T, 128x128
// tiles, BK=64, dbuf global_load_lds. Epilogue scatters to Qb/Kb/Vtb.
// ---------------------------------------------------------------------------
__global__ __launch_bounds__(256)
void qkv_gemm(const bf16* __restrict__ xb, const bf16* __restrict__ Wt,
              bf16* __restrict__ Qb, bf16* __restrict__ Kb, bf16* __restrict__ Vtb)
{
    const int m0 = blockIdx.x * 128;
    const int n0 = blockIdx.y * 128;
    __shared__ __align__(16) bf16 xa[2][128 * 64];
    __shared__ __align__(16) bf16 wb2[2][128 * 64];

    const int t = threadIdx.x, lane = t & 63, w = t >> 6;
    const int l15 = lane & 15, quad = lane >> 4;

    auto stage_a = [&](int buf, int kk) {
        #pragma unroll
        for (int j = 0; j < 4; j++) {
            int c = (j * 4 + w) * 64 + lane;
            int row = c >> 3, ch = (c & 7) ^ (row & 7);
            stage16((const char*)(xb + (size_t)(m0 + row) * D_ + kk) + ch * 16,
                    (char*)&xa[buf][0] + (j * 4 + w) * 1024);
        }
    };
    auto stage_b = [&](int buf, int kk) {
        #pragma unroll
        for (int j = 0; j < 4; j++) {
            int c = (j * 4 + w) * 64 + lane;
            int row = c >> 3, ch = (c & 7) ^ (row & 7);
            stage16((const char*)(Wt + (size_t)(n0 + row) * D_ + kk) + ch * 16,
                    (char*)&wb2[buf][0] + (j * 4 + w) * 1024);
        }
    };

    const floatx4 fz = {0.f, 0.f, 0.f, 0.f};
    floatx4 acc[2][8];
    #pragma unroll
    for (int mt = 0; mt < 2; mt++)
        #pragma unroll
        for (int nt = 0; nt < 8; nt++) acc[mt][nt] = fz;

    stage_a(0, 0); stage_b(0, 0);
    for (int kt = 0; kt < 16; kt++) {
        int cur = kt & 1;
        __syncthreads();
        if (kt < 15) { stage_a(cur ^ 1, (kt + 1) * 64); stage_b(cur ^ 1, (kt + 1) * 64); }
        #pragma unroll
        for (int ks = 0; ks < 2; ks++) {
            bf16x8 a0 = ldsfrag(&xa[cur][0], w * 32 + l15,      ks * 4 + quad);
            bf16x8 a1 = ldsfrag(&xa[cur][0], w * 32 + 16 + l15, ks * 4 + quad);
            #pragma unroll
            for (int nt = 0; nt < 8; nt++) {
                bf16x8 b = ldsfrag(&wb2[cur][0], nt * 16 + l15, ks * 4 + quad);
                acc[0][nt] = MFMA16(a0, b, acc[0][nt]);
                acc[1][nt] = MFMA16(a1, b, acc[1][nt]);
            }
        }
    }

    const int which = n0 >> 10;   // uniform per block (n0 multiple of 128)
    #pragma unroll
    for (int nt = 0; nt < 8; nt++) {
        int n = n0 + nt * 16 + l15;
        int hh = (n >> 6) & 15, col = n & 63;
        #pragma unroll
        for (int mt = 0; mt < 2; mt++)
            #pragma unroll
            for (int r = 0; r < 4; r++) {
                int s = m0 + w * 32 + mt * 16 + quad * 4 + r;
                bf16 val = __float2bfloat16(acc[mt][nt][r]);
                if (which == 0)      Qb[((size_t)hh * S_ + s) * 64 + col] = val;
                else if (which == 1) Kb[((size_t)hh * S_ + s) * 64 + col] = val;
                else                 Vtb[((size_t)hh * 64 + col) * S_ + s] = val;
            }
    }
}

// ---------------------------------------------------------------------------
// Kernel 2: attention. Sᵀ = K·Qᵀ via swapped MFMA operands (Q loop-invariant
// in registers as the B-side). C-layout of Sᵀ gives each lane 4 consecutive
// KEYS of one q-row -> packed ds_write_b64 of P into pl[q][key] (swizzled).
// Wave w owns q-columns w*32..+31 == its own PV rows (no cross-wave P dep).
// No-max softmax (scale+log2e folded into Wq), exp2, per-lane partial sums.
// NKT = key tiles per block; FULL: normalize+write Cat; else fp32 partials.
// ---------------------------------------------------------------------------
template<int NKT, bool FULL>
__global__ __launch_bounds__(256)
void attn(const bf16* __restrict__ Qb, const bf16* __restrict__ Kb,
          const bf16* __restrict__ Vtb, bf16* __restrict__ Cat,
          float* __restrict__ Opart, float* __restrict__ lpart)
{
    const int m0 = blockIdx.x * 128;
    const int h  = blockIdx.y;
    const int half = blockIdx.z;
    const int keybase = half * (NKT * 64);

    __shared__ __align__(16) bf16 ka[2][64 * 64];   // 16 KB swizzled [key][dk]
    __shared__ __align__(16) bf16 vt[2][64 * 64];   // 16 KB swizzled [dv][key]
    __shared__ __align__(16) bf16 pl[128 * 64];     // 16 KB swizzled [q][key]
    __shared__ float lsum[128];

    const int t = threadIdx.x, lane = t & 63, w = t >> 6;
    const int l15 = lane & 15, quad = lane >> 4;

    auto stage_kv = [&](int buf, int key0) {
        const char* kg = (const char*)(Kb + ((size_t)h * S_ + key0) * 64);
        #pragma unroll
        for (int j = 0; j < 2; j++) {
            int c = (j * 4 + w) * 64 + lane;
            int row = c >> 3, ch = (c & 7) ^ (row & 7);
            stage16(kg + row * 128 + ch * 16, (char*)&ka[buf][0] + (j * 4 + w) * 1024);
        }
        const char* vg = (const char*)(Vtb + (size_t)h * 64 * S_ + key0);
        #pragma unroll
        for (int j = 0; j < 2; j++) {
            int c = (j * 4 + w) * 64 + lane;
            int row = c >> 3, ch = (c & 7) ^ (row & 7);
            stage16(vg + (size_t)row * (S_ * 2) + ch * 16, (char*)&vt[buf][0] + (j * 4 + w) * 1024);
        }
    };

    // Q fragments, loop-invariant, straight from global into registers (B-side)
    bf16x8 qf[2][2];
    #pragma unroll
    for (int nq = 0; nq < 2; nq++)
        #pragma unroll
        for (int ks = 0; ks < 2; ks++)
            qf[nq][ks] = *(const bf16x8*)(Qb +
                ((size_t)h * S_ + m0 + w * 32 + nq * 16 + l15) * 64 + ks * 32 + quad * 8);

    const floatx4 fz = {0.f, 0.f, 0.f, 0.f};
    floatx4 acc[2][4];
    float rs[2] = {0.f, 0.f};
    #pragma unroll
    for (int mt = 0; mt < 2; mt++)
        #pragma unroll
        for (int nt = 0; nt < 4; nt++) acc[mt][nt] = fz;

    stage_kv(0, keybase);
    __syncthreads();

    for (int kt = 0; kt < NKT; kt++) {
        const int cur = kt & 1;
        if (kt + 1 < NKT) stage_kv(cur ^ 1, keybase + (kt + 1) * 64);

        // Sᵀ[key][q] = K·Qᵀ : a = K-frag (rows=keys), b = Q-frag (cols=q)
        floatx4 sc[4][2];
        #pragma unroll
        for (int mk = 0; mk < 4; mk++)
            #pragma unroll
            for (int nq = 0; nq < 2; nq++) sc[mk][nq] = fz;
        #pragma unroll
        for (int ks = 0; ks < 2; ks++) {
            bf16x8 af[4];
            #pragma unroll
            for (int mk = 0; mk < 4; mk++)
                af[mk] = ldsfrag(&ka[cur][0], mk * 16 + l15, ks * 4 + quad);
            #pragma unroll
            for (int mk = 0; mk < 4; mk++)
                #pragma unroll
                for (int nq = 0; nq < 2; nq++)
                    sc[mk][nq] = MFMA16(af[mk], qf[nq][ks], sc[mk][nq]);
        }

        // p = exp2(s); per-lane partial row sums; packed b64 P-writes.
        // lane holds keys mk*16+quad*4+r (r=0..3 consecutive) of q = w*32+nq*16+l15
        #pragma unroll
        for (int mk = 0; mk < 4; mk++)
            #pragma unroll
            for (int nq = 0; nq < 2; nq++) {
                float p0 = EXP2(sc[mk][nq][0]);
                float p1 = EXP2(sc[mk][nq][1]);
                float p2 = EXP2(sc[mk][nq][2]);
                float p3 = EXP2(sc[mk][nq][3]);
                rs[nq] += (p0 + p1) + (p2 + p3);
                ushort4 pw;
                pw.x = bfbits(p0); pw.y = bfbits(p1); pw.z = bfbits(p2); pw.w = bfbits(p3);
                int q = w * 32 + nq * 16 + l15;
                int ch = 2 * mk + (quad >> 1);
                *(ushort4*)((char*)pl + q * 128 + ((ch ^ (q & 7)) << 4) + (quad & 1) * 8) = pw;
            }
        asm volatile("s_waitcnt lgkmcnt(0)" ::: "memory");  // P visible to own wave

        // O += P·V  (wave's own rows)
        #pragma unroll
        for (int ks = 0; ks < 2; ks++) {
            bf16x8 a0 = ldsfrag(pl, w * 32 + l15,      ks * 4 + quad);
            bf16x8 a1 = ldsfrag(pl, w * 32 + 16 + l15, ks * 4 + quad);
            #pragma unroll
            for (int nt = 0; nt < 4; nt++) {
                bf16x8 b = ldsfrag(&vt[cur][0], nt * 16 + l15, ks * 4 + quad);
                acc[0][nt] = MFMA16(a0, b, acc[0][nt]);
                acc[1][nt] = MFMA16(a1, b, acc[1][nt]);
            }
        }
        __syncthreads();   // staging(next) landed; all waves done with cur
    }

    // full row sums: reduce across the 4 quads (lanes l15, +16, +32, +48)
    #pragma unroll
    for (int nq = 0; nq < 2; nq++) {
        rs[nq] += __shfl_xor(rs[nq], 16);
        rs[nq] += __shfl_xor(rs[nq], 32);
        if (quad == 0) lsum[w * 32 + nq * 16 + l15] = rs[nq];
    }
    asm volatile("s_waitcnt lgkmcnt(0)" ::: "memory");

    if (FULL) {
        #pragma unroll
        for (int mt = 0; mt < 2; mt++)
            #pragma unroll
            for (int r = 0; r < 4; r++) {
                int rl = w * 32 + mt * 16 + quad * 4 + r;
                float inv = 1.0f / lsum[rl];
                #pragma unroll
                for (int nt = 0; nt < 4; nt++)
                    Cat[(size_t)(m0 + rl) * (H_ * DV_) + h * 64 + nt * 16 + l15] =
                        __float2bfloat16(acc[mt][nt][r] * inv);
            }
    } else {
        const size_t plane = (size_t)(half * H_ + h) * S_;
        #pragma unroll
        for (int mt = 0; mt < 2; mt++)
            #pragma unroll
            for (int r = 0; r < 4; r++) {
                int rl = w * 32 + mt * 16 + quad * 4 + r;
                #pragma unroll
                for (int nt = 0; nt < 4; nt++)
                    Opart[(plane + m0 + rl) * 64 + nt * 16 + l15] = acc[mt][nt][r];
            }
        #pragma unroll
        for (int nq = 0; nq < 2; nq++)
            if (quad == 0)
                lpart[plane + m0 + w * 32 + nq * 16 + l15] = rs[nq];
    }
}

// ---------------------------------------------------------------------------
// Kernel 2b: combine key-split partials -> Cat bf16
// ---------------------------------------------------------------------------
__global__ __launch_bounds__(256)
void combine(const float* __restrict__ Opart, const float* __restrict__ lpart,
             bf16* __restrict__ Cat)
{
    const int h = blockIdx.y;
    const int off = blockIdx.x * 1024 + threadIdx.x * 4;   // within [S*64]
    const int s = off >> 6, dv = off & 63;
    float4 o0 = *(const float4*)(Opart + (size_t)h * S_ * 64 + off);
    float4 o1 = *(const float4*)(Opart + (size_t)(H_ + h) * S_ * 64 + off);
    float inv = 1.0f / (lpart[(size_t)h * S_ + s] + lpart[(size_t)(H_ + h) * S_ + s]);
    ushort4 o;
    o.x = bfbits((o0.x + o1.x) * inv);
    o.y = bfbits((o0.y + o1.y) * inv);
    o.z = bfbits((o0.z + o1.z) * inv);
    o.w = bfbits((o0.w + o1.w) * inv);
    *(ushort4*)(Cat + (size_t)s * (H_ * DV_) + h * 64 + dv) = o;
}

// ---------------------------------------------------------------------------
// Kernel 3: output projection, 128x64 tiles (grid 512 = 2 blocks/CU), BK=64.
// ---------------------------------------------------------------------------
__global__ __launch_bounds__(256)
void out_proj(const bf16* __restrict__ Cat, const bf16* __restrict__ Wct,
              const float* __restrict__ bc, float* __restrict__ out)
{
    const int m0 = blockIdx.x * 128;
    const int n0 = blockIdx.y * 64;
    __shared__ __align__(16) bf16 ca[2][128 * 64];   // 32 KB
    __shared__ __align__(16) bf16 wb2[2][64 * 64];   // 16 KB

    const int t = threadIdx.x, lane = t & 63, w = t >> 6;
    const int l15 = lane & 15, quad = lane >> 4;

    auto stage_a = [&](int buf, int kk) {
        #pragma unroll
        for (int j = 0; j < 4; j++) {
            int c = (j * 4 + w) * 64 + lane;
            int row = c >> 3, ch = (c & 7) ^ (row & 7);
            stage16((const char*)(Cat + (size_t)(m0 + row) * D_ + kk) + ch * 16,
                    (char*)&ca[buf][0] + (j * 4 + w) * 1024);
        }
    };
    auto stage_b = [&](int buf, int kk) {
        #pragma unroll
        for (int j = 0; j < 2; j++) {
            int c = (j * 4 + w) * 64 + lane;
            int row = c >> 3, ch = (c & 7) ^ (row & 7);
            stage16((const char*)(Wct + (size_t)(n0 + row) * D_ + kk) + ch * 16,
                    (char*)&wb2[buf][0] + (j * 4 + w) * 1024);
        }
    };

    const floatx4 fz = {0.f, 0.f, 0.f, 0.f};
    floatx4 acc[2][4];
    #pragma unroll
    for (int mt = 0; mt < 2; mt++)
        #pragma unroll
        for (int nt = 0; nt < 4; nt++) acc[mt][nt] = fz;

    stage_a(0, 0); stage_b(0, 0);
    for (int kt = 0; kt < 16; kt++) {
        int cur = kt & 1;
        __syncthreads();
        if (kt < 15) { stage_a(cur ^ 1, (kt + 1) * 64); stage_b(cur ^ 1, (kt + 1) * 64); }
        #pragma unroll
        for (int ks = 0; ks < 2; ks++) {
            bf16x8 a0 = ldsfrag(&ca[cur][0], w * 32 + l15,      ks * 4 + quad);
            bf16x8 a1 = ldsfrag(&ca[cur][0], w * 32 + 16 + l15, ks * 4 + quad);
            #pragma unroll
            for (int nt = 0; nt < 4; nt++) {
                bf16x8 b = ldsfrag(&wb2[cur][0], nt * 16 + l15, ks * 4 + quad);
                acc[0][nt] = MFMA16(a0, b, acc[0][nt]);
                acc[1][nt] = MFMA16(a1, b, acc[1][nt]);
            }
        }
    }

    #pragma unroll
    for (int nt = 0; nt < 4; nt++) {
        int col = n0 + nt * 16 + l15;
        float bias = bc[col];
        #pragma unroll
        for (int mt = 0; mt < 2; mt++)
            #pragma unroll
            for (int r = 0; r < 4; r++) {
                int row = m0 + w * 32 + mt * 16 + quad * 4 + r;
                out[(size_t)row * D_ + col] = acc[mt][nt][r] + bias;
            }
    }
}

extern "C" void kernel_launch(void* const* d_in, const int* in_sizes, int n_in,
                              void* d_out, int out_size, void* d_ws, size_t ws_size,
                              hipStream_t stream)
{
    const float* x  = (const float*)d_in[0];
    const float* Wq = (const float*)d_in[1];
    const float* Wk = (const float*)d_in[2];
    const float* Wv = (const float*)d_in[3];
    const float* Wc = (const float*)d_in[4];
    const float* bc = (const float*)d_in[5];
    float* out = (float*)d_out;

    // workspace (bytes): xb/Cat 8M, Wt 6M, Wct 2M, Qb/Kb/Vtb 24M, [Opart 32M, lpart .5M]
    bf16* xb  = (bf16*)d_ws;                          // [S][D], aliased as Cat later
    bf16* Cat = xb;
    bf16* Wt  = xb  + (size_t)S_ * D_;                // [3072][1024]
    bf16* Wct = Wt  + (size_t)3 * H_ * 64 * D_;       // [1024][1024]
    bf16* Qb  = Wct + (size_t)D_ * H_ * DV_;          // [H][S][64]
    bf16* Kb  = Qb  + (size_t)H_ * S_ * 64;           // [H][S][64]
    bf16* Vtb = Kb  + (size_t)H_ * S_ * 64;           // [H][64][S]
    float* Opart = (float*)(Vtb + (size_t)H_ * 64 * S_);  // [2][H][S][64] fp32
    float* lpart = Opart + (size_t)2 * H_ * S_ * 64;      // [2][H][S]

    const size_t need_split = (size_t)((char*)(lpart + (size_t)2 * H_ * S_) - (char*)d_ws);
    const bool split = ws_size >= need_split;

    cvt_x<<<dim3(S_ * D_ / (256 * 8)), 256, 0, stream>>>(x, xb);
    tr_qkv<<<dim3(16, 1, 48), 256, 0, stream>>>(Wq, Wk, Wv, Wt);
    tr_wc<<<dim3(16, 16), 256, 0, stream>>>(Wc, Wct);

    qkv_gemm<<<dim3(S_ / 128, 3072 / 128), 256, 0, stream>>>(xb, Wt, Qb, Kb, Vtb);

    if (split) {
        attn<32, false><<<dim3(S_ / 128, H_, 2), 256, 0, stream>>>(
            Qb, Kb, Vtb, Cat, Opart, lpart);
        combine<<<dim3(S_ * 64 / 1024, H_), 256, 0, stream>>>(Opart, lpart, Cat);
    } else {
        attn<64, true><<<dim3(S_ / 128, H_, 1), 256, 0, stream>>>(
            Qb, Kb, Vtb, Cat, Opart, lpart);
    }

    out_proj<<<dim3(S_ / 128, D_ / 64), 256, 0, stream>>>(Cat, Wct, bc, out);
}